// Round 6
// baseline (171.213 us; speedup 1.0000x reference)
//
#include <hip/hip_runtime.h>
#include <math.h>

#define HH 64
#define WW 64
#define NB 4
#define NV ((HH-1)*WW)      // 4032 vertical candidates
#define NHZ (HH*(WW-1))     // 4032 horizontal candidates
#define NP (NV+NHZ)         // 8064 candidates per image
#define EPSF 1e-3f
#define BANDF 3.0f
#define BIGF 1e10f
#define SENTV 1e5f          // sentinel coord; d2 ~ 2e10 > BIGF, never selected
#define NGCAP 5056          // LDS G capacity (mult of 64); +64 prefetch pad = 40960 B
#define PPB 32              // P points per k_nn block (16 grps x 2 P/lane)
#define NBLK_P ((NP+PPB-1)/PPB)   // 252
#define GRID_NN (NB*NBLK_P)       // 1008

// ---- ws layout ----
// float2 Pp[NB][NP], float2 Gp[NB][NP]
// int NPv[NB], NGv[NB]
// float acc[12] : S[4], l1n[4], l1[4]
// int ctr

__device__ __forceinline__ bool cand_point(const float* __restrict__ s, int p,
                                           float& pr, float& pc) {
  float v1, v2; int i, j; bool vert = (p < NV);
  if (vert) {
    i = p >> 6; j = p & 63;
    v1 = s[i*WW + j]; v2 = s[(i+1)*WW + j];
  } else {
    int q = p - NV; i = q / (WW-1); j = q - i*(WW-1);
    v1 = s[i*WW + j]; v2 = s[i*WW + j + 1];
  }
  float a1 = fabsf(v1), a2 = fabsf(v2);
  // sign(v1)*sign(v2)<0 == v1*v2<0 when neither |v|<=EPS (no underflow then)
  bool valid = (v1*v2 < 0.0f) || (a1 <= EPSF) || (a2 <= EPSF);
  float a = a1 / fmaxf(a1 + a2, 1e-8f);
  a = fminf(fmaxf(a, 0.0f), 1.0f);
  pr = vert ? ((float)i + a) : (float)i;
  pc = vert ? (float)j       : ((float)j + a);
  return valid;
}

__device__ __forceinline__ void normal_at(const float* __restrict__ s, int r, int c,
                                          float& nr, float& nc) {
  float grm = (r == 0)    ? (s[WW + c] - s[c])
            : (r == HH-1) ? (s[(HH-1)*WW + c] - s[(HH-2)*WW + c])
                          : 0.5f * (s[(r+1)*WW + c] - s[(r-1)*WW + c]);
  float gcm = (c == 0)    ? (s[r*WW + 1] - s[r*WW])
            : (c == WW-1) ? (s[r*WW + WW-1] - s[r*WW + WW-2])
                          : 0.5f * (s[r*WW + c + 1] - s[r*WW + c - 1]);
  nr = grm; nc = gcm;
}

// K1: 8 blocks. blk>>2==0: compact gt->Gp (+ zero acc/ctr); ==1: compact
// pred->Pp + per-batch L1 sum.
__global__ __launch_bounds__(256) void k_prep(const float* __restrict__ pred,
                                              const float* __restrict__ gt,
                                              float2* __restrict__ Pp,
                                              float2* __restrict__ Gp,
                                              int* __restrict__ NPv,
                                              int* __restrict__ NGv,
                                              float* __restrict__ acc,
                                              int* __restrict__ ctr) {
  int which = blockIdx.x >> 2;     // 0: gt, 1: pred
  int b = blockIdx.x & 3;
  const float* src = which ? (pred + b*HH*WW) : (gt + b*HH*WW);
  float2* dst = which ? (Pp + (size_t)b*NP) : (Gp + (size_t)b*NP);
  int* cnt_out = which ? NPv : NGv;

  __shared__ float2 cval[NP];                  // 64512 B
  __shared__ unsigned long long cmask[4*32];
  __shared__ int wcnt[4], wbase[4];
  int tid = threadIdx.x, lane = tid & 63, wid = tid >> 6;
  const int SPAN = NP / 4;                     // 2016
  int start = wid * SPAN, end = start + SPAN;

  int cnt = 0;
  for (int t = 0; t < 32; ++t) {               // 2016 = 31.5*64 -> guard
    int p = start + t*64 + lane;
    bool v = false; float r = 0.f, c = 0.f;
    if (p < end) v = cand_point(src, p, r, c);
    unsigned long long m = __ballot(v ? 1 : 0);
    if (v) cval[p] = make_float2(r, c);
    if (lane == 0) cmask[wid*32 + t] = m;
    cnt += __popcll(m);
  }
  if (lane == 0) wcnt[wid] = cnt;
  __syncthreads();
  if (tid == 0) {
    int run = 0;
    for (int w = 0; w < 4; ++w) { wbase[w] = run; run += wcnt[w]; }
    cnt_out[b] = run;
    if (!which) { acc[b] = 0.f; acc[4 + b] = 0.f; if (b == 0) *ctr = 0; }
  }
  __syncthreads();
  int off = wbase[wid];
  for (int t = 0; t < 32; ++t) {
    unsigned long long m = cmask[wid*32 + t];
    int p = start + t*64 + lane;
    if ((m >> lane) & 1ull)
      dst[off + __popcll(m & ((1ull << lane) - 1ull))] = cval[p];
    off += __popcll(m);
  }

  if (which) {  // L1 partial for batch b
    const float* pr = pred + b*HH*WW;
    const float* g  = gt   + b*HH*WW;
    float loc = 0.f;
    for (int p = tid; p < HH*WW; p += 256) loc += fabsf(pr[p] - g[p]);
    for (int o = 32; o; o >>= 1) loc += __shfl_down(loc, o);
    __shared__ float ws4[4];
    if (lane == 0) ws4[wid] = loc;
    __syncthreads();
    if (tid == 0) acc[8 + b] = ws4[0] + ws4[1] + ws4[2] + ws4[3];
  }
}

// K2: G in LDS (40960 B -> 4 blocks/CU). 16-way G split x 2 P per lane:
// 8 pair-evals per 2x ds_read_b128, explicit next-tile register prefetch
// (sentinel pad tile makes it branch-free). Lexicographic (d2,j) merge =
// first-index argmin. Fused finalize via completion counter.
__global__ __launch_bounds__(256) void k_nn(const float* __restrict__ pred,
                                            const float2* __restrict__ Pp,
                                            const float2* __restrict__ Gp,
                                            const int* __restrict__ NPv,
                                            const int* __restrict__ NGv,
                                            float* __restrict__ acc,
                                            int* __restrict__ ctr,
                                            float* __restrict__ out) {
  __shared__ __align__(16) float2 Gs[NGCAP + 64];   // 40960 B
  __shared__ int lastFlag;

  int bb = blockIdx.x;
  int b = bb / NBLK_P;
  int chunk = bb - b * NBLK_P;
  int npv = NPv[b], ng = NGv[b];
  int pbase = chunk * PPB;
  int tid = threadIdx.x;
  bool hasWork = (pbase < npv);     // block-uniform

  int ngs = min(ng, NGCAP);
  int ngp = (ngs + 63) & ~63;
  const float2* Gb = Gp + (size_t)b * NP;

  if (hasWork) {
    for (int i = tid; i < ngs; i += 256) Gs[i] = Gb[i];
    for (int i = ngs + tid; i < ngp + 64; i += 256) Gs[i] = make_float2(SENTV, SENTV);
  }
  __syncthreads();

  int s = tid & 15, grp = tid >> 4;
  int p0 = pbase + grp * 2;
  const float* sp = pred + b*HH*WW;
  float contribS = 0.f, contribN = 0.f;

  if (hasWork) {
    bool v0 = (p0 < npv), v1 = (p0 + 1 < npv);
    const float2* Pb = Pp + (size_t)b * NP;
    float2 P0 = v0 ? Pb[p0] : make_float2(SENTV, SENTV);
    float2 P1 = v1 ? Pb[p0 + 1] : P0;
    float p20 = P0.x*P0.x + P0.y*P0.y;
    float p21 = P1.x*P1.x + P1.y*P1.y;

    // 4 chains: (P0,A-stream),(P0,B-stream),(P1,A),(P1,B)
    float dA0 = BIGF, dB0 = BIGF, dA1 = BIGF, dB1 = BIGF;
    int   jA0 = 0x7fffffff, jB0 = 0x7fffffff, jA1 = 0x7fffffff, jB1 = 0x7fffffff;

    const float4* G4 = (const float4*)Gs;
    int nk = ngp >> 6;                 // 64 G points per iteration
    float4 ga = G4[s];                 // points 2s, 2s+1       (A-stream)
    float4 gb = G4[s + 16];           // points 32+2s, 33+2s   (B-stream)
    for (int k = 0; k < nk; ++k) {
      float4 na = G4[(k + 1) * 32 + s];        // prefetch next tile
      float4 nb = G4[(k + 1) * 32 + 16 + s];   // (tile nk = sentinels)
      int ja = (k << 6) + (s << 1);            // j of (ga.x,ga.y)
      float g2, t, dd;
      // A-stream candidate 1: (ga.x,ga.y), j=ja
      g2 = fmaf(ga.y, ga.y, ga.x * ga.x);
      t  = fmaf(ga.y, P0.y, ga.x * P0.x);
      dd = fmaf(-2.f, t, p20 + g2);
      if (dd < dA0) { dA0 = dd; jA0 = ja; }
      t  = fmaf(ga.y, P1.y, ga.x * P1.x);
      dd = fmaf(-2.f, t, p21 + g2);
      if (dd < dA1) { dA1 = dd; jA1 = ja; }
      // A-stream candidate 2: (ga.z,ga.w), j=ja+1
      g2 = fmaf(ga.w, ga.w, ga.z * ga.z);
      t  = fmaf(ga.w, P0.y, ga.z * P0.x);
      dd = fmaf(-2.f, t, p20 + g2);
      if (dd < dA0) { dA0 = dd; jA0 = ja + 1; }
      t  = fmaf(ga.w, P1.y, ga.z * P1.x);
      dd = fmaf(-2.f, t, p21 + g2);
      if (dd < dA1) { dA1 = dd; jA1 = ja + 1; }
      // B-stream candidate 1: (gb.x,gb.y), j=ja+32
      g2 = fmaf(gb.y, gb.y, gb.x * gb.x);
      t  = fmaf(gb.y, P0.y, gb.x * P0.x);
      dd = fmaf(-2.f, t, p20 + g2);
      if (dd < dB0) { dB0 = dd; jB0 = ja + 32; }
      t  = fmaf(gb.y, P1.y, gb.x * P1.x);
      dd = fmaf(-2.f, t, p21 + g2);
      if (dd < dB1) { dB1 = dd; jB1 = ja + 32; }
      // B-stream candidate 2: (gb.z,gb.w), j=ja+33
      g2 = fmaf(gb.w, gb.w, gb.z * gb.z);
      t  = fmaf(gb.w, P0.y, gb.z * P0.x);
      dd = fmaf(-2.f, t, p20 + g2);
      if (dd < dB0) { dB0 = dd; jB0 = ja + 33; }
      t  = fmaf(gb.w, P1.y, gb.z * P1.x);
      dd = fmaf(-2.f, t, p21 + g2);
      if (dd < dB1) { dB1 = dd; jB1 = ja + 33; }
      ga = na; gb = nb;
    }
    // merge A/B chains per P (lexicographic (d2,j) = first-index argmin)
    float bd0 = dA0; int bj0 = jA0;
    if (dB0 < bd0 || (dB0 == bd0 && jB0 < bj0)) { bd0 = dB0; bj0 = jB0; }
    float bd1 = dA1; int bj1 = jA1;
    if (dB1 < bd1 || (dB1 == bd1 && jB1 < bj1)) { bd1 = dB1; bj1 = jB1; }
    // global tail (only if ng > NGCAP; never on this data). Tail j > any LDS j,
    // so strict < keeps first-index semantics.
    for (int j = NGCAP + s; j < ng; j += 16) {
      float2 g = Gb[j];
      float g2 = fmaf(g.y, g.y, g.x * g.x), t, dd;
      t  = fmaf(g.y, P0.y, g.x * P0.x);
      dd = fmaf(-2.f, t, p20 + g2);
      if (dd < bd0) { bd0 = dd; bj0 = j; }
      t  = fmaf(g.y, P1.y, g.x * P1.x);
      dd = fmaf(-2.f, t, p21 + g2);
      if (dd < bd1) { bd1 = dd; bj1 = j; }
    }
    // 16-lane butterfly (group = lanes sharing grp), lexicographic
    for (int moff = 1; moff <= 8; moff <<= 1) {
      float od = __shfl_xor(bd0, moff); int oj = __shfl_xor(bj0, moff);
      if (od < bd0 || (od == bd0 && oj < bj0)) { bd0 = od; bj0 = oj; }
      od = __shfl_xor(bd1, moff); oj = __shfl_xor(bj1, moff);
      if (od < bd1 || (od == bd1 && oj < bj1)) { bd1 = od; bj1 = oj; }
    }

    // tails: lane s==0 handles P0, lane s==1 handles P1
    bool  myV = (s == 0) ? v0 : ((s == 1) ? v1 : false);
    if (myV) {
      float myD = (s == 0) ? bd0 : bd1;
      int   myJ = (s == 0) ? bj0 : bj1;
      float2 myP = (s == 0) ? P0 : P1;
      float minP = sqrtf(fmaxf(myD, 0.f));
      if (minP <= BANDF) {
        float2 gbest = (myJ < ngs) ? Gs[myJ] : Gb[min(myJ, ng - 1)];
        float prr = myP.x, pcc = myP.y;
        int r0 = min(max((int)floorf(prr), 0), HH-1);
        int c0 = min(max((int)floorf(pcc), 0), WW-1);
        int r1 = min(r0 + 1, HH-1), c1 = min(c0 + 1, WW-1);
        float dr = prr - (float)r0, dc = pcc - (float)c0;
        float w00 = (1.f-dr)*(1.f-dc), w01 = (1.f-dr)*dc;
        float w10 = dr*(1.f-dc),       w11 = dr*dc;
        float nar, nac, nbr, nbc, ncr, ncc, ndr, ndc;
        normal_at(sp, r0, c0, nar, nac);
        normal_at(sp, r0, c1, nbr, nbc);
        normal_at(sp, r1, c0, ncr, ncc);
        normal_at(sp, r1, c1, ndr, ndc);
        float nr  = w00*nar + w01*nbr + w10*ncr + w11*ndr;
        float nc2 = w00*nac + w01*nbc + w10*ncc + w11*ndc;
        float bilin = w00*sp[r0*WW+c0] + w01*sp[r0*WW+c1]
                    + w10*sp[r1*WW+c0] + w11*sp[r1*WW+c1];
        float dlr = gbest.x - prr, dlc = gbest.y - pcc;   // G[idx] - P
        contribN = fabsf(nr) + fabsf(nc2);
        contribS = (dlr*nr + dlc*nc2) * bilin;
      }
    }
  }

  // wave sum (nonzero only at s<2 lanes), one atomic per wave
  for (int o = 1; o < 64; o <<= 1) {
    contribS += __shfl_xor(contribS, o);
    contribN += __shfl_xor(contribN, o);
  }
  if ((tid & 63) == 0 && (contribS != 0.f || contribN != 0.f)) {
    atomicAdd(&acc[b],     contribS);
    atomicAdd(&acc[4 + b], contribN);
  }

  // fused finalize: last block computes the scalar
  __threadfence();
  if (tid == 0) {
    int old = atomicAdd(ctr, 1);
    lastFlag = (old == GRID_NN - 1) ? 1 : 0;
  }
  __syncthreads();
  if (lastFlag && tid == 0) {
    float ps = 0.f, l1 = 0.f;
    for (int bi = 0; bi < NB; ++bi) {
      float S = atomicAdd(&acc[bi], 0.f);       // coherent read
      float N = atomicAdd(&acc[4 + bi], 0.f);
      ps += -(S / (N + 1e-8f));                 // pseudo_b (SCALE=1, NORM_N)
      l1 += acc[8 + bi];                        // written by k_prep
    }
    out[0] = ps * (1.0f / NB) + l1 * (1.0f / (NB * HH * WW));
  }
}

extern "C" void kernel_launch(void* const* d_in, const int* in_sizes, int n_in,
                              void* d_out, int out_size, void* d_ws, size_t ws_size,
                              hipStream_t stream) {
  const float* pred = (const float*)d_in[0];
  const float* gt   = (const float*)d_in[1];
  float* out = (float*)d_out;

  float2* Pp = (float2*)d_ws;
  float2* Gp = Pp + (size_t)NB * NP;
  int*    NPv = (int*)(Gp + (size_t)NB * NP);
  int*    NGv = NPv + NB;
  float*  acc = (float*)(NGv + NB);     // 12 floats: S[4], l1n[4], l1[4]
  int*    ctr = (int*)(acc + 12);

  k_prep<<<2 * NB, 256, 0, stream>>>(pred, gt, Pp, Gp, NPv, NGv, acc, ctr);
  k_nn<<<GRID_NN, 256, 0, stream>>>(pred, Pp, Gp, NPv, NGv, acc, ctr, out);
}

// Round 9
// 122.067 us; speedup vs baseline: 1.4026x; 1.4026x over previous
//
#include <hip/hip_runtime.h>
#include <math.h>

#define HH 64
#define WW 64
#define NB 4
#define NV ((HH-1)*WW)      // 4032 vertical candidates
#define NHZ (HH*(WW-1))     // 4032 horizontal candidates
#define NP (NV+NHZ)         // 8064 candidates per image
#define EPSF 1e-3f
#define BANDF 3.0f
#define BIGF 1e10f
#define NCELL 256           // 16x16 cells of size 4; radius 3 < 4 => 3x3 ring exact
#define GRID_NN (NB*32)     // 128 blocks x 256 thr = one thread per candidate

// ---- ws layout ----
// float4 binEnt[NB][NP]  : (r, c, j-as-int-bits, g2)  516096 B
// int    offs[NB][NCELL+1]
// float  acc[12] : S[4], l1n[4], l1[4]
// int    ctr

__device__ __forceinline__ bool cand_point(const float* __restrict__ s, int p,
                                           float& pr, float& pc) {
  float v1, v2; int i, j; bool vert = (p < NV);
  if (vert) {
    i = p >> 6; j = p & 63;
    v1 = s[i*WW + j]; v2 = s[(i+1)*WW + j];
  } else {
    int q = p - NV; i = q / (WW-1); j = q - i*(WW-1);
    v1 = s[i*WW + j]; v2 = s[i*WW + j + 1];
  }
  float a1 = fabsf(v1), a2 = fabsf(v2);
  // sign(v1)*sign(v2)<0 == v1*v2<0 when neither |v|<=EPS (no underflow then)
  bool valid = (v1*v2 < 0.0f) || (a1 <= EPSF) || (a2 <= EPSF);
  float a = a1 / fmaxf(a1 + a2, 1e-8f);
  a = fminf(fmaxf(a, 0.0f), 1.0f);
  pr = vert ? ((float)i + a) : (float)i;
  pc = vert ? (float)j       : ((float)j + a);
  return valid;
}

__device__ __forceinline__ void normal_at(const float* __restrict__ s, int r, int c,
                                          float& nr, float& nc) {
  float grm = (r == 0)    ? (s[WW + c] - s[c])
            : (r == HH-1) ? (s[(HH-1)*WW + c] - s[(HH-2)*WW + c])
                          : 0.5f * (s[(r+1)*WW + c] - s[(r-1)*WW + c]);
  float gcm = (c == 0)    ? (s[r*WW + 1] - s[r*WW])
            : (c == WW-1) ? (s[r*WW + WW-1] - s[r*WW + WW-2])
                          : 0.5f * (s[r*WW + c + 1] - s[r*WW + c - 1]);
  nr = grm; nc = gcm;
}

// K1: 4 blocks, one per batch. Compact-j scan of gt candidates, CSR-bin them
// into 16x16 cells (entries carry r,c,j,g2), write offs; also per-batch L1
// sum and acc/ctr zeroing.
__global__ __launch_bounds__(256) void k_prep(const float* __restrict__ pred,
                                              const float* __restrict__ gt,
                                              float4* __restrict__ binEnt,
                                              int* __restrict__ offs_g,
                                              float* __restrict__ acc,
                                              int* __restrict__ ctr) {
  int b = blockIdx.x;
  const float* g = gt + b*HH*WW;

  __shared__ float2 cval[NP];                  // 64512 B
  __shared__ unsigned long long cmask[4*32];
  __shared__ int wcnt[4], wbase[4];
  __shared__ int cellCnt[NCELL];               // counts, then fill cursors
  __shared__ int cellOff[NCELL+1];
  __shared__ float ws4[4];

  int tid = threadIdx.x, lane = tid & 63, wid = tid >> 6;
  for (int i = tid; i < NCELL; i += 256) cellCnt[i] = 0;
  __syncthreads();

  const int SPAN = NP / 4;                     // 2016
  int start = wid * SPAN, end = start + SPAN;

  // pass 1: validity, coords, per-wave counts, per-cell counts
  int cnt = 0;
  for (int t = 0; t < 32; ++t) {
    int p = start + t*64 + lane;
    bool v = false; float r = 0.f, c = 0.f;
    if (p < end) v = cand_point(g, p, r, c);
    unsigned long long m = __ballot(v ? 1 : 0);
    if (v) {
      cval[p] = make_float2(r, c);
      int cell = (((int)r) >> 2) * 16 + (((int)c) >> 2);
      atomicAdd(&cellCnt[cell], 1);
    }
    if (lane == 0) cmask[wid*32 + t] = m;
    cnt += __popcll(m);
  }
  if (lane == 0) wcnt[wid] = cnt;
  __syncthreads();
  if (tid == 0) {
    int run = 0;
    for (int w = 0; w < 4; ++w) { wbase[w] = run; run += wcnt[w]; }
    int s2 = 0;
    for (int i = 0; i < NCELL; ++i) { cellOff[i] = s2; s2 += cellCnt[i]; }
    cellOff[NCELL] = s2;
    acc[b] = 0.f; acc[4 + b] = 0.f;
    if (b == 0) *ctr = 0;
  }
  __syncthreads();
  for (int i = tid; i < NCELL; i += 256) cellCnt[i] = cellOff[i];   // fill cursors
  for (int i = tid; i < NCELL + 1; i += 256) offs_g[b*(NCELL+1) + i] = cellOff[i];
  __syncthreads();

  // pass 2: scatter (r, c, j, g2) into CSR bins (order within cell arbitrary;
  // NN uses lexicographic (d2,j) so first-index tie-break is preserved)
  float4* Eb = binEnt + (size_t)b * NP;
  int off = wbase[wid];
  for (int t = 0; t < 32; ++t) {
    unsigned long long m = cmask[wid*32 + t];
    int p = start + t*64 + lane;
    if ((m >> lane) & 1ull) {
      int j = off + __popcll(m & ((1ull << lane) - 1ull));   // compacted j, monotone in p
      float2 rc = cval[p];
      int cell = (((int)rc.x) >> 2) * 16 + (((int)rc.y) >> 2);
      int slot = atomicAdd(&cellCnt[cell], 1);
      float g2 = fmaf(rc.y, rc.y, rc.x * rc.x);              // same rounding as r6 loop
      Eb[slot] = make_float4(rc.x, rc.y, __int_as_float(j), g2);
    }
    off += __popcll(m);
  }

  // L1 partial for batch b
  const float* pr = pred + b*HH*WW;
  float loc = 0.f;
  for (int p = tid; p < HH*WW; p += 256) loc += fabsf(pr[p] - g[p]);
  for (int o = 32; o; o >>= 1) loc += __shfl_down(loc, o);
  if (lane == 0) ws4[wid] = loc;
  __syncthreads();
  if (tid == 0) acc[8 + b] = ws4[0] + ws4[1] + ws4[2] + ws4[3];
}

// K2: one thread per P candidate (recomputes its P from pred — no Pp array).
// NN search = 3 contiguous CSR row-spans (3x3 cell ring), ~142 entries instead
// of 4096. Lexicographic (d2,j) = reference first-index argmin. Fused finalize.
__global__ __launch_bounds__(256) void k_nn(const float* __restrict__ pred,
                                            const float4* __restrict__ binEnt,
                                            const int* __restrict__ offs_g,
                                            float* __restrict__ acc,
                                            int* __restrict__ ctr,
                                            float* __restrict__ out) {
  __shared__ int soffs[NCELL+1];
  __shared__ int lastFlag;

  int bb = blockIdx.x;
  int b = bb >> 5, chunk = bb & 31;
  int tid = threadIdx.x;
  int p = chunk*256 + tid;                   // 8192 threads >= NP
  const float* sp = pred + b*HH*WW;

  for (int i = tid; i < NCELL + 1; i += 256) soffs[i] = offs_g[b*(NCELL+1) + i];
  __syncthreads();

  float contribS = 0.f, contribN = 0.f;
  float prr = 0.f, pcc = 0.f;
  bool vP = (p < NP) ? cand_point(sp, p, prr, pcc) : false;

  if (vP) {
    float p2 = prr*prr + pcc*pcc;
    const float4* E = binEnt + (size_t)b * NP;
    int cr = ((int)prr) >> 2, ccell = ((int)pcc) >> 2;
    int rlo = max(cr - 1, 0), rhi = min(cr + 1, 15);
    int clo = max(ccell - 1, 0), chi = min(ccell + 1, 15);
    float bd = BIGF; int bj = 0x7fffffff, be = 0;
    for (int rr = rlo; rr <= rhi; ++rr) {
      int beg = soffs[rr*16 + clo];
      int end = soffs[rr*16 + chi + 1];
      #pragma unroll 2
      for (int e = beg; e < end; ++e) {
        float4 ge = E[e];
        float t  = fmaf(ge.y, pcc, ge.x * prr);
        float dd = fmaf(-2.f, t, p2 + ge.w);
        int   j  = __float_as_int(ge.z);
        if (dd < bd || (dd == bd && j < bj)) { bd = dd; bj = j; be = e; }
      }
    }
    // ring-min == global min whenever it's <= BAND (radius 3 < cell 4);
    // ring-min > BAND => reference-masked => contribute 0 (also covers empty ring)
    float minP = sqrtf(fmaxf(bd, 0.f));
    if (minP <= BANDF) {
      float4 gb = E[be];
      int r0 = min(max((int)floorf(prr), 0), HH-1);
      int c0 = min(max((int)floorf(pcc), 0), WW-1);
      int r1 = min(r0 + 1, HH-1), c1 = min(c0 + 1, WW-1);
      float dr = prr - (float)r0, dc = pcc - (float)c0;
      float w00 = (1.f-dr)*(1.f-dc), w01 = (1.f-dr)*dc;
      float w10 = dr*(1.f-dc),       w11 = dr*dc;
      float nar, nac, nbr, nbc, ncr, ncc, ndr, ndc;
      normal_at(sp, r0, c0, nar, nac);
      normal_at(sp, r0, c1, nbr, nbc);
      normal_at(sp, r1, c0, ncr, ncc);
      normal_at(sp, r1, c1, ndr, ndc);
      float nr  = w00*nar + w01*nbr + w10*ncr + w11*ndr;
      float nc2 = w00*nac + w01*nbc + w10*ncc + w11*ndc;
      float bilin = w00*sp[r0*WW+c0] + w01*sp[r0*WW+c1]
                  + w10*sp[r1*WW+c0] + w11*sp[r1*WW+c1];
      float dlr = gb.x - prr, dlc = gb.y - pcc;   // G[idx] - P
      contribN = fabsf(nr) + fabsf(nc2);
      contribS = (dlr*nr + dlc*nc2) * bilin;
    }
  }

  // wave sum, one atomic per wave
  for (int o = 1; o < 64; o <<= 1) {
    contribS += __shfl_xor(contribS, o);
    contribN += __shfl_xor(contribN, o);
  }
  if ((tid & 63) == 0 && (contribS != 0.f || contribN != 0.f)) {
    atomicAdd(&acc[b],     contribS);
    atomicAdd(&acc[4 + b], contribN);
  }

  // fused finalize: last of the 128 blocks computes the scalar
  __threadfence();
  if (tid == 0) {
    int old = atomicAdd(ctr, 1);
    lastFlag = (old == GRID_NN - 1) ? 1 : 0;
  }
  __syncthreads();
  if (lastFlag && tid == 0) {
    float ps = 0.f, l1 = 0.f;
    for (int bi = 0; bi < NB; ++bi) {
      float S = atomicAdd(&acc[bi], 0.f);       // coherent read
      float N = atomicAdd(&acc[4 + bi], 0.f);
      ps += -(S / (N + 1e-8f));                 // pseudo_b (SCALE=1, NORM_N)
      l1 += acc[8 + bi];                        // written by k_prep
    }
    out[0] = ps * (1.0f / NB) + l1 * (1.0f / (NB * HH * WW));
  }
}

extern "C" void kernel_launch(void* const* d_in, const int* in_sizes, int n_in,
                              void* d_out, int out_size, void* d_ws, size_t ws_size,
                              hipStream_t stream) {
  const float* pred = (const float*)d_in[0];
  const float* gt   = (const float*)d_in[1];
  float* out = (float*)d_out;

  float4* binEnt = (float4*)d_ws;                                  // NB*NP*16
  int*    offs_g = (int*)((char*)d_ws + (size_t)NB * NP * 16);     // NB*(NCELL+1)
  float*  acc    = (float*)(offs_g + NB * (NCELL + 1));            // 12 floats
  int*    ctr    = (int*)(acc + 12);

  k_prep<<<NB, 256, 0, stream>>>(pred, gt, binEnt, offs_g, acc, ctr);
  k_nn<<<GRID_NN, 256, 0, stream>>>(pred, binEnt, offs_g, acc, ctr, out);
}